// Round 1
// baseline (6414.196 us; speedup 1.0000x reference)
//
#include <hip/hip_runtime.h>

#define D 256
#define NI_SRC 100000
#define NI_DST 50000
#define NU0 50000
#define NU1 25000
#define EII 800000
#define EIU0 800000
#define EIU1 400000
#define DOUT 128

// ---------------- degree accumulation ----------------
__global__ void deg_kernel(const int* __restrict__ dst, int E, float* __restrict__ deg, int dmax) {
    int i = blockIdx.x * blockDim.x + threadIdx.x;
    int stride = gridDim.x * blockDim.x;
    for (; i < E; i += stride) {
        int d = dst[i];
        if (d < dmax) atomicAdd(&deg[d], 1.0f);
    }
}

// deg -> 1/max(deg,1)  (in place)
__global__ void rdeg_kernel(float* deg, int n) {
    int i = blockIdx.x * blockDim.x + threadIdx.x;
    if (i < n) deg[i] = 1.0f / fmaxf(deg[i], 1.0f);
}

// ---------------- feature scatter-add ----------------
// one 64-lane group per edge; each lane handles 4 consecutive floats
__global__ void scatter_kernel(const float* __restrict__ X, const int* __restrict__ src,
                               const int* __restrict__ dst, int E,
                               float* __restrict__ agg, int dmax) {
    int lane = threadIdx.x & 63;
    int egrp = (blockIdx.x * blockDim.x + threadIdx.x) >> 6;
    int nGrp = (gridDim.x * blockDim.x) >> 6;
    for (int e = egrp; e < E; e += nGrp) {
        int dd = dst[e];
        if (dd >= dmax) continue;
        int ss = src[e];
        const float4 v = *reinterpret_cast<const float4*>(X + (size_t)ss * D + lane * 4);
        float* o = agg + (size_t)dd * D + lane * 4;
        atomicAdd(o + 0, v.x);
        atomicAdd(o + 1, v.y);
        atomicAdd(o + 2, v.z);
        atomicAdd(o + 3, v.w);
    }
}

// ---------------- fused SAGE GEMM ----------------
// C = act( A1 @ W1 + rdeg_row * (A2 @ W2) + bias )
// A1,A2: M x 256 row-major; W1,W2: 256 x N row-major; C: M x N
template<bool HAS_AGG, bool RELU>
__global__ __launch_bounds__(256) void sage_gemm(
    const float* __restrict__ A1, const float* __restrict__ A2,
    const float* __restrict__ rdeg,
    const float* __restrict__ W1, const float* __restrict__ W2,
    const float* __restrict__ bias,
    float* __restrict__ C, int M, int N)
{
    const int K = D;
    const int BM = 64, BN = 64, BK = 32;
    __shared__ float sA[BK][BM + 4];
    __shared__ float sB[BK][BN + 4];

    const int tid = threadIdx.x;
    const int tx = tid & 15, ty = tid >> 4;
    const int brow = blockIdx.x * BM;
    const int bcol = blockIdx.y * BN;

    float acc[4][4] = {};

    const int nPass = HAS_AGG ? 2 : 1;
    for (int pass = 0; pass < nPass; ++pass) {
        const float* __restrict__ A = pass ? A2 : A1;
        const float* __restrict__ W = pass ? W2 : W1;
        for (int kt = 0; kt < K; kt += BK) {
            // A tile: BM x BK, stored transposed sA[k][m]
#pragma unroll
            for (int i = 0; i < 8; ++i) {
                int e = tid + i * 256;
                int k = e & 31, m = e >> 5;
                int row = brow + m;
                float v = 0.f;
                if (row < M) {
                    v = A[(size_t)row * K + kt + k];
                    if (pass) v *= rdeg[row];
                }
                sA[k][m] = v;
            }
            // W tile: BK x BN
#pragma unroll
            for (int i = 0; i < 8; ++i) {
                int e = tid + i * 256;
                int n = e & 63, k = e >> 6;
                sB[k][n] = W[(size_t)(kt + k) * N + bcol + n];
            }
            __syncthreads();
#pragma unroll
            for (int kk = 0; kk < BK; ++kk) {
                float4 a4 = *reinterpret_cast<const float4*>(&sA[kk][ty * 4]);
                float4 b4 = *reinterpret_cast<const float4*>(&sB[kk][tx * 4]);
                float av[4] = {a4.x, a4.y, a4.z, a4.w};
                float bv[4] = {b4.x, b4.y, b4.z, b4.w};
#pragma unroll
                for (int i = 0; i < 4; ++i)
#pragma unroll
                    for (int j = 0; j < 4; ++j)
                        acc[i][j] += av[i] * bv[j];
            }
            __syncthreads();
        }
    }

#pragma unroll
    for (int i = 0; i < 4; ++i) {
        int row = brow + ty * 4 + i;
        if (row >= M) continue;
#pragma unroll
        for (int j = 0; j < 4; ++j) {
            int col = bcol + tx * 4 + j;
            float v = acc[i][j] + bias[col];
            if (RELU) v = fmaxf(v, 0.f);
            C[(size_t)row * N + col] = v;
        }
    }
}

extern "C" void kernel_launch(void* const* d_in, const int* in_sizes, int n_in,
                              void* d_out, int out_size, void* d_ws, size_t ws_size,
                              hipStream_t stream) {
    const float* x_item = (const float*)d_in[0];
    const float* x_user = (const float*)d_in[1];
    const int* src_ii  = (const int*)d_in[2];
    const int* dst_ii  = (const int*)d_in[3];
    const int* src_iu0 = (const int*)d_in[4];
    const int* dst_iu0 = (const int*)d_in[5];
    const int* src_iu1 = (const int*)d_in[6];
    const int* dst_iu1 = (const int*)d_in[7];
    const float* Wn1 = (const float*)d_in[8];
    const float* Ws1 = (const float*)d_in[9];
    const float* b1  = (const float*)d_in[10];
    const float* Wn2 = (const float*)d_in[11];
    const float* Ws2 = (const float*)d_in[12];
    const float* b2  = (const float*)d_in[13];
    const float* Wn3 = (const float*)d_in[14];
    const float* Ws3 = (const float*)d_in[15];
    const float* b3  = (const float*)d_in[16];
    const float* Wlin = (const float*)d_in[17];
    const float* blin = (const float*)d_in[18];
    float* out = (float*)d_out;

    // workspace layout (floats)
    float* ws = (float*)d_ws;
    float* aggbuf  = ws;                                   // 50000*256 (agg1; later agg2|agg3; later user_x3)
    float* item_x  = aggbuf + (size_t)NI_DST * D;          // 50000*256
    float* user_x2 = item_x + (size_t)NI_DST * D;          // 25000*256
    float* deg1    = user_x2 + (size_t)NU1 * D;            // 50000
    float* deg2    = deg1 + NI_DST;                        // 25000
    float* deg3    = deg2 + NU1;                           // 25000

    float* agg2 = aggbuf;
    float* agg3 = aggbuf + (size_t)NU1 * D;
    float* user_x3 = aggbuf;  // overlays dead agg2 during GEMM3

    // zero agg1 + all degrees
    hipMemsetAsync(aggbuf, 0, (size_t)NI_DST * D * sizeof(float), stream);
    hipMemsetAsync(deg1, 0, (size_t)(NI_DST + 2 * NU1) * sizeof(float), stream);

    // degrees (layer2 only needs dst < 25000)
    deg_kernel<<<512, 256, 0, stream>>>(dst_ii, EII, deg1, NI_DST);
    deg_kernel<<<512, 256, 0, stream>>>(dst_iu0, EIU0, deg2, NU1);
    deg_kernel<<<512, 256, 0, stream>>>(dst_iu1, EIU1, deg3, NU1);
    rdeg_kernel<<<(NI_DST + 2 * NU1 + 255) / 256, 256, 0, stream>>>(deg1, NI_DST + 2 * NU1);

    // layer 1: item->item
    scatter_kernel<<<2048, 256, 0, stream>>>(x_item, src_ii, dst_ii, EII, aggbuf, NI_DST);
    dim3 g1((NI_DST + 63) / 64, D / 64);
    sage_gemm<true, true><<<g1, 256, 0, stream>>>(x_item, aggbuf, deg1, Ws1, Wn1, b1, item_x, NI_DST, D);

    // re-zero agg region for layers 2+3
    hipMemsetAsync(aggbuf, 0, (size_t)NI_DST * D * sizeof(float), stream);
    scatter_kernel<<<2048, 256, 0, stream>>>(x_item, src_iu0, dst_iu0, EIU0, agg2, NU1);
    scatter_kernel<<<2048, 256, 0, stream>>>(item_x, src_iu1, dst_iu1, EIU1, agg3, NU1);

    // layer 2 (only first 25000 users are consumed downstream)
    dim3 g2((NU1 + 63) / 64, D / 64);
    sage_gemm<true, true><<<g2, 256, 0, stream>>>(x_user, agg2, deg2, Ws2, Wn2, b2, user_x2, NU1, D);

    // layer 3: item_x -> user1
    sage_gemm<true, true><<<g2, 256, 0, stream>>>(user_x2, agg3, deg3, Ws3, Wn3, b3, user_x3, NU1, D);

    // head: user_x3 @ Wlin + blin
    dim3 g4((NU1 + 63) / 64, DOUT / 64);
    sage_gemm<false, false><<<g4, 256, 0, stream>>>(user_x3, nullptr, nullptr, Wlin, nullptr, blin, out, NU1, DOUT);
}

// Round 2
// 1476.354 us; speedup vs baseline: 4.3446x; 4.3446x over previous
//
#include <hip/hip_runtime.h>

#define D 256
#define NI_SRC 100000
#define NI_DST 50000
#define NU0 50000
#define NU1 25000
#define EII 800000
#define EIU0 800000
#define EIU1 400000
#define DOUT 128

// ---------------- int degree histogram ----------------
__global__ void hist_kernel(const int* __restrict__ dst, int E, int* __restrict__ cnt, int dmax) {
    int i = blockIdx.x * blockDim.x + threadIdx.x;
    int stride = gridDim.x * blockDim.x;
    for (; i < E; i += stride) {
        int d = dst[i];
        if (d < dmax) atomicAdd(&cnt[d], 1);
    }
}

// ---------------- single-workgroup exclusive scan (n <= ~1e5) ----------------
__global__ __launch_bounds__(1024) void scan_kernel(const int* __restrict__ cnt, int* __restrict__ rs, int n) {
    __shared__ int buf[1024];
    __shared__ int carry_s;
    int tid = threadIdx.x;
    if (tid == 0) { carry_s = 0; rs[0] = 0; }
    __syncthreads();
    for (int base = 0; base < n; base += 1024) {
        int i = base + tid;
        int v = (i < n) ? cnt[i] : 0;
        buf[tid] = v;
        __syncthreads();
        // Hillis-Steele inclusive scan
        for (int off = 1; off < 1024; off <<= 1) {
            int t = (tid >= off) ? buf[tid - off] : 0;
            __syncthreads();
            buf[tid] += t;
            __syncthreads();
        }
        int carry = carry_s;                 // read before update
        if (i < n) rs[i + 1] = carry + buf[tid];
        int total = buf[1023];
        __syncthreads();
        if (tid == 0) carry_s = carry + total;
        __syncthreads();
    }
}

// ---------------- bucket edges into CSR ----------------
__global__ void bucket_kernel(const int* __restrict__ src, const int* __restrict__ dst, int E,
                              const int* __restrict__ rs, int* __restrict__ cur,
                              int* __restrict__ csr, int dmax) {
    int i = blockIdx.x * blockDim.x + threadIdx.x;
    int stride = gridDim.x * blockDim.x;
    for (; i < E; i += stride) {
        int d = dst[i];
        if (d < dmax) {
            int p = atomicAdd(&cur[d], 1);
            csr[rs[d] + p] = src[i];
        }
    }
}

// ---------------- wave-per-row mean gather ----------------
// out[row] = mean_{e in row} X[csr[e]]   (deg clamped to 1)
__global__ __launch_bounds__(256) void gather_csr(const float* __restrict__ X,
                                                  const int* __restrict__ csr,
                                                  const int* __restrict__ rs,
                                                  float* __restrict__ out, int nrows) {
    int wid = (blockIdx.x * blockDim.x + threadIdx.x) >> 6;
    int lane = threadIdx.x & 63;
    if (wid >= nrows) return;
    int s = rs[wid], e = rs[wid + 1];
    float4 acc = {0.f, 0.f, 0.f, 0.f};
    for (int j = s; j < e; j += 64) {
        int myid = (j + lane < e) ? csr[j + lane] : 0;
        int cnt = min(64, e - j);
        for (int t = 0; t < cnt; ++t) {
            int sid = __shfl(myid, t, 64);
            const float4 v = *reinterpret_cast<const float4*>(X + (size_t)sid * D + lane * 4);
            acc.x += v.x; acc.y += v.y; acc.z += v.z; acc.w += v.w;
        }
    }
    float r = 1.0f / fmaxf((float)(e - s), 1.0f);
    float4 o = {acc.x * r, acc.y * r, acc.z * r, acc.w * r};
    *reinterpret_cast<float4*>(out + (size_t)wid * D + lane * 4) = o;
}

// ---------------- fused SAGE GEMM ----------------
// C = act( A1 @ W1 + A2 @ W2 + bias )   (A2/agg already mean-normalized)
template<bool HAS_AGG, bool RELU>
__global__ __launch_bounds__(256) void sage_gemm(
    const float* __restrict__ A1, const float* __restrict__ A2,
    const float* __restrict__ W1, const float* __restrict__ W2,
    const float* __restrict__ bias,
    float* __restrict__ C, int M, int N)
{
    const int K = D;
    const int BM = 64, BN = 64, BK = 32;
    __shared__ float sA[BK][BM + 4];
    __shared__ float sB[BK][BN + 4];

    const int tid = threadIdx.x;
    const int tx = tid & 15, ty = tid >> 4;
    const int brow = blockIdx.x * BM;
    const int bcol = blockIdx.y * BN;

    float acc[4][4] = {};

    const int nPass = HAS_AGG ? 2 : 1;
    for (int pass = 0; pass < nPass; ++pass) {
        const float* __restrict__ A = pass ? A2 : A1;
        const float* __restrict__ W = pass ? W2 : W1;
        for (int kt = 0; kt < K; kt += BK) {
#pragma unroll
            for (int i = 0; i < 8; ++i) {
                int e = tid + i * 256;
                int k = e & 31, m = e >> 5;
                int row = brow + m;
                float v = 0.f;
                if (row < M) v = A[(size_t)row * K + kt + k];
                sA[k][m] = v;
            }
#pragma unroll
            for (int i = 0; i < 8; ++i) {
                int e = tid + i * 256;
                int n = e & 63, k = e >> 6;
                sB[k][n] = W[(size_t)(kt + k) * N + bcol + n];
            }
            __syncthreads();
#pragma unroll
            for (int kk = 0; kk < BK; ++kk) {
                float4 a4 = *reinterpret_cast<const float4*>(&sA[kk][ty * 4]);
                float4 b4 = *reinterpret_cast<const float4*>(&sB[kk][tx * 4]);
                float av[4] = {a4.x, a4.y, a4.z, a4.w};
                float bv[4] = {b4.x, b4.y, b4.z, b4.w};
#pragma unroll
                for (int i = 0; i < 4; ++i)
#pragma unroll
                    for (int j = 0; j < 4; ++j)
                        acc[i][j] += av[i] * bv[j];
            }
            __syncthreads();
        }
    }

#pragma unroll
    for (int i = 0; i < 4; ++i) {
        int row = brow + ty * 4 + i;
        if (row >= M) continue;
#pragma unroll
        for (int j = 0; j < 4; ++j) {
            int col = bcol + tx * 4 + j;
            float v = acc[i][j] + bias[col];
            if (RELU) v = fmaxf(v, 0.f);
            C[(size_t)row * N + col] = v;
        }
    }
}

extern "C" void kernel_launch(void* const* d_in, const int* in_sizes, int n_in,
                              void* d_out, int out_size, void* d_ws, size_t ws_size,
                              hipStream_t stream) {
    const float* x_item = (const float*)d_in[0];
    const float* x_user = (const float*)d_in[1];
    const int* src_ii  = (const int*)d_in[2];
    const int* dst_ii  = (const int*)d_in[3];
    const int* src_iu0 = (const int*)d_in[4];
    const int* dst_iu0 = (const int*)d_in[5];
    const int* src_iu1 = (const int*)d_in[6];
    const int* dst_iu1 = (const int*)d_in[7];
    const float* Wn1 = (const float*)d_in[8];
    const float* Ws1 = (const float*)d_in[9];
    const float* b1  = (const float*)d_in[10];
    const float* Wn2 = (const float*)d_in[11];
    const float* Ws2 = (const float*)d_in[12];
    const float* b2  = (const float*)d_in[13];
    const float* Wn3 = (const float*)d_in[14];
    const float* Ws3 = (const float*)d_in[15];
    const float* b3  = (const float*)d_in[16];
    const float* Wlin = (const float*)d_in[17];
    const float* blin = (const float*)d_in[18];
    float* out = (float*)d_out;

    // workspace layout (floats)
    float* ws = (float*)d_ws;
    float* aggbuf  = ws;                                   // 50000*256 (agg1; then agg2|agg3; then user_x3)
    float* item_x  = aggbuf + (size_t)NI_DST * D;          // 50000*256
    float* user_x2 = item_x + (size_t)NI_DST * D;          // 25000*256

    // CSR int scratch overlays user_x2 (dead until GEMM2, all gathers done by then)
    int* cnt = (int*)user_x2;          // 50000
    int* rs  = cnt + NI_DST;           // 50001
    int* cur = rs + NI_DST + 1;        // 50000
    int* csr = cur + NI_DST;           // 800000

    float* agg2 = aggbuf;                                  // 25000*256
    float* agg3 = aggbuf + (size_t)NU1 * D;                // 25000*256
    float* user_x3 = aggbuf;                               // overlays dead agg2 during GEMM3

    dim3 gemm_g1((NI_DST + 63) / 64, D / 64);
    dim3 gemm_g2((NU1 + 63) / 64, D / 64);
    dim3 gemm_g4((NU1 + 63) / 64, DOUT / 64);

    // ---- graph 1: item->item (dst < 50000) ----
    hipMemsetAsync(cnt, 0, sizeof(int) * 2 * NI_DST + sizeof(int), stream);  // cnt+rs[0]; cur zeroed below
    hipMemsetAsync(cur, 0, sizeof(int) * NI_DST, stream);
    hist_kernel<<<512, 256, 0, stream>>>(dst_ii, EII, cnt, NI_DST);
    scan_kernel<<<1, 1024, 0, stream>>>(cnt, rs, NI_DST);
    bucket_kernel<<<512, 256, 0, stream>>>(src_ii, dst_ii, EII, rs, cur, csr, NI_DST);
    gather_csr<<<(NI_DST * 64 + 255) / 256, 256, 0, stream>>>(x_item, csr, rs, aggbuf, NI_DST);
    sage_gemm<true, true><<<gemm_g1, 256, 0, stream>>>(x_item, aggbuf, Ws1, Wn1, b1, item_x, NI_DST, D);

    // ---- graph 2: item->user0, only dst < 25000 consumed ----
    hipMemsetAsync(cnt, 0, sizeof(int) * NU1, stream);
    hipMemsetAsync(cur, 0, sizeof(int) * NU1, stream);
    hist_kernel<<<512, 256, 0, stream>>>(dst_iu0, EIU0, cnt, NU1);
    scan_kernel<<<1, 1024, 0, stream>>>(cnt, rs, NU1);
    bucket_kernel<<<512, 256, 0, stream>>>(src_iu0, dst_iu0, EIU0, rs, cur, csr, NU1);
    gather_csr<<<(NU1 * 64 + 255) / 256, 256, 0, stream>>>(x_item, csr, rs, agg2, NU1);

    // ---- graph 3: item1->user1 (needs item_x, ready after GEMM1) ----
    hipMemsetAsync(cnt, 0, sizeof(int) * NU1, stream);
    hipMemsetAsync(cur, 0, sizeof(int) * NU1, stream);
    hist_kernel<<<512, 256, 0, stream>>>(dst_iu1, EIU1, cnt, NU1);
    scan_kernel<<<1, 1024, 0, stream>>>(cnt, rs, NU1);
    bucket_kernel<<<512, 256, 0, stream>>>(src_iu1, dst_iu1, EIU1, rs, cur, csr, NU1);
    gather_csr<<<(NU1 * 64 + 255) / 256, 256, 0, stream>>>(item_x, csr, rs, agg3, NU1);

    // ---- layer 2 GEMM (csr scratch now dead; user_x2 written here) ----
    sage_gemm<true, true><<<gemm_g2, 256, 0, stream>>>(x_user, agg2, Ws2, Wn2, b2, user_x2, NU1, D);

    // ---- layer 3 GEMM ----
    sage_gemm<true, true><<<gemm_g2, 256, 0, stream>>>(user_x2, agg3, Ws3, Wn3, b3, user_x3, NU1, D);

    // ---- head ----
    sage_gemm<false, false><<<gemm_g4, 256, 0, stream>>>(user_x3, nullptr, Wlin, nullptr, blin, out, NU1, DOUT);
}

// Round 3
// 565.032 us; speedup vs baseline: 11.3519x; 2.6129x over previous
//
#include <hip/hip_runtime.h>

#define D 256
#define NI_SRC 100000
#define NI_DST 50000
#define NU1 25000
#define EII 800000
#define EIU0 800000
#define EIU1 400000
#define DOUT 128

typedef __bf16 bf16x8 __attribute__((ext_vector_type(8)));
typedef float f32x4 __attribute__((ext_vector_type(4)));

__device__ __forceinline__ unsigned short f2bf(float x) {
    unsigned u = __builtin_bit_cast(unsigned, x);
    u += 0x7FFFu + ((u >> 16) & 1u);   // RNE
    return (unsigned short)(u >> 16);
}
__device__ __forceinline__ float bflo(unsigned u) { return __builtin_bit_cast(float, u << 16); }
__device__ __forceinline__ float bfhi(unsigned u) { return __builtin_bit_cast(float, u & 0xFFFF0000u); }

// ---------------- f32 -> bf16 bulk convert (8 elems/thread) ----------------
__global__ __launch_bounds__(256) void cvt_kernel(const float* __restrict__ in,
                                                  unsigned short* __restrict__ out, long n8) {
    long i = (long)blockIdx.x * blockDim.x + threadIdx.x;
    if (i >= n8) return;
    const float4 f1 = *reinterpret_cast<const float4*>(in + i * 8);
    const float4 f2 = *reinterpret_cast<const float4*>(in + i * 8 + 4);
    uint4 v;
    v.x = f2bf(f1.x) | ((unsigned)f2bf(f1.y) << 16);
    v.y = f2bf(f1.z) | ((unsigned)f2bf(f1.w) << 16);
    v.z = f2bf(f2.x) | ((unsigned)f2bf(f2.y) << 16);
    v.w = f2bf(f2.z) | ((unsigned)f2bf(f2.w) << 16);
    *reinterpret_cast<uint4*>(out + i * 8) = v;
}

// ---------------- weight convert + transpose: Wt[n][k] = bf16(W[k][n]) ----------------
__global__ __launch_bounds__(256) void wtr_kernel(const float* __restrict__ W,
                                                  unsigned short* __restrict__ Wt, int K, int N) {
    int t = blockIdx.x * blockDim.x + threadIdx.x;
    if (t >= K * N) return;
    int n = t / K, k = t % K;  // consecutive t -> consecutive k: coalesced writes
    Wt[t] = f2bf(W[(size_t)k * N + n]);
}

// ---------------- int degree histogram ----------------
__global__ void hist_kernel(const int* __restrict__ dst, int E, int* __restrict__ cnt, int dmax) {
    int i = blockIdx.x * blockDim.x + threadIdx.x;
    int stride = gridDim.x * blockDim.x;
    for (; i < E; i += stride) {
        int d = dst[i];
        if (d < dmax) atomicAdd(&cnt[d], 1);
    }
}

// ---------------- single-workgroup exclusive scan, 4 elems/thread ----------------
__global__ __launch_bounds__(1024) void scan_kernel(const int* __restrict__ cnt, int* __restrict__ rs, int n) {
    __shared__ int buf[1024];
    __shared__ int carry_s;
    int tid = threadIdx.x;
    if (tid == 0) { carry_s = 0; rs[0] = 0; }
    __syncthreads();
    for (int base = 0; base < n; base += 4096) {
        int i0 = base + tid * 4;
        int v[4];
#pragma unroll
        for (int q = 0; q < 4; ++q) { int i = i0 + q; v[q] = (i < n) ? cnt[i] : 0; }
        int s = v[0] + v[1] + v[2] + v[3];
        buf[tid] = s;
        __syncthreads();
        for (int off = 1; off < 1024; off <<= 1) {
            int t = (tid >= off) ? buf[tid - off] : 0;
            __syncthreads();
            buf[tid] += t;
            __syncthreads();
        }
        int carry = carry_s;
        int excl = carry + buf[tid] - s;
#pragma unroll
        for (int q = 0; q < 4; ++q) { int i = i0 + q; excl += v[q]; if (i < n) rs[i + 1] = excl; }
        int total = buf[1023];
        __syncthreads();
        if (tid == 0) carry_s = carry + total;
        __syncthreads();
    }
}

// ---------------- bucket edges into CSR ----------------
__global__ void bucket_kernel(const int* __restrict__ src, const int* __restrict__ dst, int E,
                              const int* __restrict__ rs, int* __restrict__ cur,
                              int* __restrict__ csr, int dmax) {
    int i = blockIdx.x * blockDim.x + threadIdx.x;
    int stride = gridDim.x * blockDim.x;
    for (; i < E; i += stride) {
        int d = dst[i];
        if (d < dmax) {
            int p = atomicAdd(&cur[d], 1);
            csr[rs[d] + p] = src[i];
        }
    }
}

// ---------------- wave-per-row mean gather (bf16 in, bf16 out, f32 accum) ----------------
__global__ __launch_bounds__(256) void gather_csr(const unsigned short* __restrict__ X,
                                                  const int* __restrict__ csr,
                                                  const int* __restrict__ rs,
                                                  unsigned short* __restrict__ out, int nrows) {
    int wid = (blockIdx.x * blockDim.x + threadIdx.x) >> 6;
    int lane = threadIdx.x & 63;
    if (wid >= nrows) return;
    int s = rs[wid], e = rs[wid + 1];
    float a0 = 0.f, a1 = 0.f, a2 = 0.f, a3 = 0.f;
    for (int j = s; j < e; j += 64) {
        int myid = (j + lane < e) ? csr[j + lane] : 0;
        int cnt = min(64, e - j);
        for (int t = 0; t < cnt; ++t) {
            int sid = __shfl(myid, t, 64);
            const uint2 v = *reinterpret_cast<const uint2*>(X + (size_t)sid * D + lane * 4);
            a0 += bflo(v.x); a1 += bfhi(v.x);
            a2 += bflo(v.y); a3 += bfhi(v.y);
        }
    }
    float r = 1.0f / fmaxf((float)(e - s), 1.0f);
    uint2 o;
    o.x = f2bf(a0 * r) | ((unsigned)f2bf(a1 * r) << 16);
    o.y = f2bf(a2 * r) | ((unsigned)f2bf(a3 * r) << 16);
    *reinterpret_cast<uint2*>(out + (size_t)wid * D + lane * 4) = o;
}

// ---------------- MFMA SAGE GEMM ----------------
// C = act( A1 @ W1^T' + A2 @ W2^T' + bias ),  Wt stored [n][k], K=256
template<bool A1F32, bool HAS_AGG, bool RELU, bool OUTF32>
__global__ __launch_bounds__(256) void sage_gemm(
    const unsigned short* __restrict__ A1b, const float* __restrict__ A1f,
    const unsigned short* __restrict__ A2,
    const unsigned short* __restrict__ W1t, const unsigned short* __restrict__ W2t,
    const float* __restrict__ bias,
    unsigned short* __restrict__ Cb, float* __restrict__ Cf,
    int M, int N)
{
    __shared__ unsigned short sA[128 * 40];  // [row][40] padded, 80B stride
    __shared__ unsigned short sB[128 * 40];  // [n][40]
    const int tid = threadIdx.x;
    const int lane = tid & 63;
    const int wid = tid >> 6;
    const int wrow = (wid >> 1) * 64;
    const int wcol = (wid & 1) * 64;
    const int brow = blockIdx.x * 128;
    const int bcol = blockIdx.y * 128;

    f32x4 acc[4][4] = {};

    const int r0 = tid >> 2;        // 0..63
    const int k0 = (tid & 3) * 8;   // 0,8,16,24

    const int nPass = HAS_AGG ? 2 : 1;
    for (int pass = 0; pass < nPass; ++pass) {
        const unsigned short* __restrict__ Wt = pass ? W2t : W1t;
        for (int kt = 0; kt < 256; kt += 32) {
#pragma unroll
            for (int c = 0; c < 2; ++c) {
                int row = r0 + c * 64;
                int grow = brow + row;
                uint4 val = {0u, 0u, 0u, 0u};
                if (pass == 0) {
                    if (A1F32) {
                        if (grow < M) {
                            const float4 f1 = *reinterpret_cast<const float4*>(A1f + (size_t)grow * 256 + kt + k0);
                            const float4 f2 = *reinterpret_cast<const float4*>(A1f + (size_t)grow * 256 + kt + k0 + 4);
                            val.x = f2bf(f1.x) | ((unsigned)f2bf(f1.y) << 16);
                            val.y = f2bf(f1.z) | ((unsigned)f2bf(f1.w) << 16);
                            val.z = f2bf(f2.x) | ((unsigned)f2bf(f2.y) << 16);
                            val.w = f2bf(f2.z) | ((unsigned)f2bf(f2.w) << 16);
                        }
                    } else {
                        if (grow < M) val = *reinterpret_cast<const uint4*>(A1b + (size_t)grow * 256 + kt + k0);
                    }
                } else {
                    if (grow < M) val = *reinterpret_cast<const uint4*>(A2 + (size_t)grow * 256 + kt + k0);
                }
                *reinterpret_cast<uint4*>(sA + row * 40 + k0) = val;
                // B tile: same (row -> n) decomposition
                *reinterpret_cast<uint4*>(sB + row * 40 + k0) =
                    *reinterpret_cast<const uint4*>(Wt + (size_t)(bcol + row) * 256 + kt + k0);
            }
            __syncthreads();
            const int fr = lane & 15;
            const int fk = (lane >> 4) * 8;
            bf16x8 af[4], bfr[4];
#pragma unroll
            for (int f = 0; f < 4; ++f) {
                af[f]  = __builtin_bit_cast(bf16x8, *reinterpret_cast<const uint4*>(sA + (wrow + f * 16 + fr) * 40 + fk));
                bfr[f] = __builtin_bit_cast(bf16x8, *reinterpret_cast<const uint4*>(sB + (wcol + f * 16 + fr) * 40 + fk));
            }
#pragma unroll
            for (int mi = 0; mi < 4; ++mi)
#pragma unroll
                for (int ni = 0; ni < 4; ++ni)
                    acc[mi][ni] = __builtin_amdgcn_mfma_f32_16x16x32_bf16(af[mi], bfr[ni], acc[mi][ni], 0, 0, 0);
            __syncthreads();
        }
    }

    // epilogue: C row=(lane>>4)*4+j, col=lane&15
    const int cr = (lane >> 4) * 4;
    const int cc = lane & 15;
#pragma unroll
    for (int mi = 0; mi < 4; ++mi) {
#pragma unroll
        for (int j = 0; j < 4; ++j) {
            int grow = brow + wrow + mi * 16 + cr + j;
            if (grow >= M) continue;
#pragma unroll
            for (int ni = 0; ni < 4; ++ni) {
                int gcol = bcol + wcol + ni * 16 + cc;
                float v = acc[mi][ni][j] + bias[gcol];
                if (RELU) v = fmaxf(v, 0.f);
                if (OUTF32) Cf[(size_t)grow * N + gcol] = v;
                else Cb[(size_t)grow * N + gcol] = f2bf(v);
            }
        }
    }
}

extern "C" void kernel_launch(void* const* d_in, const int* in_sizes, int n_in,
                              void* d_out, int out_size, void* d_ws, size_t ws_size,
                              hipStream_t stream) {
    const float* x_item = (const float*)d_in[0];
    const float* x_user = (const float*)d_in[1];
    const int* src_ii  = (const int*)d_in[2];
    const int* dst_ii  = (const int*)d_in[3];
    const int* src_iu0 = (const int*)d_in[4];
    const int* dst_iu0 = (const int*)d_in[5];
    const int* src_iu1 = (const int*)d_in[6];
    const int* dst_iu1 = (const int*)d_in[7];
    const float* Wn1 = (const float*)d_in[8];
    const float* Ws1 = (const float*)d_in[9];
    const float* b1  = (const float*)d_in[10];
    const float* Wn2 = (const float*)d_in[11];
    const float* Ws2 = (const float*)d_in[12];
    const float* b2  = (const float*)d_in[13];
    const float* Wn3 = (const float*)d_in[14];
    const float* Ws3 = (const float*)d_in[15];
    const float* b3  = (const float*)d_in[16];
    const float* Wlin = (const float*)d_in[17];
    const float* blin = (const float*)d_in[18];
    float* out = (float*)d_out;

    // ---- workspace layout (116.05 MB < proven 128.4 MB) ----
    unsigned short* xb_item = (unsigned short*)d_ws;             // 100000*256
    unsigned short* aggbuf  = xb_item + (size_t)NI_SRC * D;      // 50000*256
    unsigned short* item_x  = aggbuf + (size_t)NI_DST * D;       // 50000*256
    unsigned short* user_x2 = item_x + (size_t)NI_DST * D;       // 25000*256
    unsigned short* wts     = user_x2 + (size_t)NU1 * D;         // 6*65536 + 32768

    // CSR int scratch overlays user_x2 (dead until GEMM2; CSR dead by then)
    int* cnt = (int*)user_x2;          // 50000
    int* rs  = cnt + NI_DST;           // 50001
    int* cur = rs + NI_DST + 1;        // 50000
    int* csr = cur + NI_DST;           // 800000

    unsigned short* Wt_s1 = wts;
    unsigned short* Wt_n1 = wts + 65536;
    unsigned short* Wt_s2 = wts + 2 * 65536;
    unsigned short* Wt_n2 = wts + 3 * 65536;
    unsigned short* Wt_s3 = wts + 4 * 65536;
    unsigned short* Wt_n3 = wts + 5 * 65536;
    unsigned short* Wt_li = wts + 6 * 65536;   // 128x256

    unsigned short* agg2 = aggbuf;                      // 25000*256
    unsigned short* agg3 = aggbuf + (size_t)NU1 * D;    // 25000*256
    unsigned short* user_x3 = aggbuf;                   // overlays dead agg2 during GEMM3

    // ---- conversions ----
    long n8 = (long)NI_SRC * D / 8;
    cvt_kernel<<<(int)((n8 + 255) / 256), 256, 0, stream>>>(x_item, xb_item, n8);
    wtr_kernel<<<256, 256, 0, stream>>>(Ws1, Wt_s1, 256, 256);
    wtr_kernel<<<256, 256, 0, stream>>>(Wn1, Wt_n1, 256, 256);
    wtr_kernel<<<256, 256, 0, stream>>>(Ws2, Wt_s2, 256, 256);
    wtr_kernel<<<256, 256, 0, stream>>>(Wn2, Wt_n2, 256, 256);
    wtr_kernel<<<256, 256, 0, stream>>>(Ws3, Wt_s3, 256, 256);
    wtr_kernel<<<256, 256, 0, stream>>>(Wn3, Wt_n3, 256, 256);
    wtr_kernel<<<128, 256, 0, stream>>>(Wlin, Wt_li, 256, 128);

    dim3 g1((NI_DST + 127) / 128, 2);
    dim3 g2((NU1 + 127) / 128, 2);
    dim3 g4((NU1 + 127) / 128, 1);

    // ---- graph 1: item->item ----
    hipMemsetAsync(cnt, 0, sizeof(int) * NI_DST, stream);
    hipMemsetAsync(cur, 0, sizeof(int) * NI_DST, stream);
    hist_kernel<<<512, 256, 0, stream>>>(dst_ii, EII, cnt, NI_DST);
    scan_kernel<<<1, 1024, 0, stream>>>(cnt, rs, NI_DST);
    bucket_kernel<<<512, 256, 0, stream>>>(src_ii, dst_ii, EII, rs, cur, csr, NI_DST);
    gather_csr<<<(NI_DST * 64 + 255) / 256, 256, 0, stream>>>(xb_item, csr, rs, aggbuf, NI_DST);
    sage_gemm<false, true, true, false><<<g1, 256, 0, stream>>>(
        xb_item, nullptr, aggbuf, Wt_s1, Wt_n1, b1, item_x, nullptr, NI_DST, D);

    // ---- graph 2: item->user0 (only dst < 25000 consumed) ----
    hipMemsetAsync(cnt, 0, sizeof(int) * NU1, stream);
    hipMemsetAsync(cur, 0, sizeof(int) * NU1, stream);
    hist_kernel<<<512, 256, 0, stream>>>(dst_iu0, EIU0, cnt, NU1);
    scan_kernel<<<1, 1024, 0, stream>>>(cnt, rs, NU1);
    bucket_kernel<<<512, 256, 0, stream>>>(src_iu0, dst_iu0, EIU0, rs, cur, csr, NU1);
    gather_csr<<<(NU1 * 64 + 255) / 256, 256, 0, stream>>>(xb_item, csr, rs, agg2, NU1);

    // ---- graph 3: item1->user1 ----
    hipMemsetAsync(cnt, 0, sizeof(int) * NU1, stream);
    hipMemsetAsync(cur, 0, sizeof(int) * NU1, stream);
    hist_kernel<<<512, 256, 0, stream>>>(dst_iu1, EIU1, cnt, NU1);
    scan_kernel<<<1, 1024, 0, stream>>>(cnt, rs, NU1);
    bucket_kernel<<<512, 256, 0, stream>>>(src_iu1, dst_iu1, EIU1, rs, cur, csr, NU1);
    gather_csr<<<(NU1 * 64 + 255) / 256, 256, 0, stream>>>(item_x, csr, rs, agg3, NU1);

    // ---- layer 2 GEMM (x_user is f32, converted in staging; writes user_x2 -> CSR now dead) ----
    sage_gemm<true, true, true, false><<<g2, 256, 0, stream>>>(
        nullptr, x_user, agg2, Wt_s2, Wt_n2, b2, user_x2, nullptr, NU1, D);

    // ---- layer 3 GEMM ----
    sage_gemm<false, true, true, false><<<g2, 256, 0, stream>>>(
        user_x2, nullptr, agg3, Wt_s3, Wt_n3, b3, user_x3, nullptr, NU1, D);

    // ---- head: f32 output ----
    sage_gemm<false, false, false, true><<<g4, 256, 0, stream>>>(
        user_x3, nullptr, nullptr, Wt_li, nullptr, blin, nullptr, out, NU1, DOUT);
}

// Round 4
// 474.135 us; speedup vs baseline: 13.5282x; 1.1917x over previous
//
#include <hip/hip_runtime.h>

#define D 256
#define NI_SRC 100000
#define NI_DST 50000
#define NU1 25000
#define EII 800000
#define EIU0 800000
#define EIU1 400000
#define DOUT 128

typedef __bf16 bf16x8 __attribute__((ext_vector_type(8)));
typedef float f32x4 __attribute__((ext_vector_type(4)));

__device__ __forceinline__ unsigned short f2bf(float x) {
    unsigned u = __builtin_bit_cast(unsigned, x);
    u += 0x7FFFu + ((u >> 16) & 1u);   // RNE
    return (unsigned short)(u >> 16);
}
__device__ __forceinline__ float bflo(unsigned u) { return __builtin_bit_cast(float, u << 16); }
__device__ __forceinline__ float bfhi(unsigned u) { return __builtin_bit_cast(float, u & 0xFFFF0000u); }

// ---------------- f32 -> bf16 bulk convert (8 elems/thread) ----------------
__global__ __launch_bounds__(256) void cvt_kernel(const float* __restrict__ in,
                                                  unsigned short* __restrict__ out, long n8) {
    long i = (long)blockIdx.x * blockDim.x + threadIdx.x;
    if (i >= n8) return;
    const float4 f1 = *reinterpret_cast<const float4*>(in + i * 8);
    const float4 f2 = *reinterpret_cast<const float4*>(in + i * 8 + 4);
    uint4 v;
    v.x = f2bf(f1.x) | ((unsigned)f2bf(f1.y) << 16);
    v.y = f2bf(f1.z) | ((unsigned)f2bf(f1.w) << 16);
    v.z = f2bf(f2.x) | ((unsigned)f2bf(f2.y) << 16);
    v.w = f2bf(f2.z) | ((unsigned)f2bf(f2.w) << 16);
    *reinterpret_cast<uint4*>(out + i * 8) = v;
}

// ---------------- all weights: convert + transpose in one kernel ----------------
// out layout: Ws1,Wn1,Ws2,Wn2,Ws3,Wn3 (65536 each, [n][k]) then Wlin (32768, [n][k])
__global__ __launch_bounds__(256) void wcvt_all(const float* __restrict__ W0, const float* __restrict__ W1,
                                                const float* __restrict__ W2, const float* __restrict__ W3,
                                                const float* __restrict__ W4, const float* __restrict__ W5,
                                                const float* __restrict__ W6,
                                                unsigned short* __restrict__ out) {
    int t = blockIdx.x * blockDim.x + threadIdx.x;
    const float* W; int NN; int base;
    if (t < 393216) {
        int w = t >> 16; base = w << 16;
        W = (w == 0) ? W0 : (w == 1) ? W1 : (w == 2) ? W2 : (w == 3) ? W3 : (w == 4) ? W4 : W5;
        NN = 256;
    } else if (t < 425984) { base = 393216; W = W6; NN = 128; }
    else return;
    int i = t - base;
    int n = i >> 8, k = i & 255;
    out[t] = f2bf(W[(size_t)k * NN + n]);
}

// ---------------- 3-graph degree histogram ----------------
__global__ void hist_all(const int* __restrict__ d1, int* __restrict__ c1,
                         const int* __restrict__ d2, int* __restrict__ c2,
                         const int* __restrict__ d3, int* __restrict__ c3) {
    int i0 = blockIdx.x * blockDim.x + threadIdx.x;
    int stride = gridDim.x * blockDim.x;
    for (int i = i0; i < EII; i += stride) atomicAdd(&c1[d1[i]], 1);
    for (int i = i0; i < EIU0; i += stride) { int d = d2[i]; if (d < NU1) atomicAdd(&c2[d], 1); }
    for (int i = i0; i < EIU1; i += stride) atomicAdd(&c3[d3[i]], 1);
}

// ---------------- 3-segment exclusive scan (block b -> segment b), 4 elems/thread ----------------
__global__ __launch_bounds__(1024) void scan3_kernel(const int* __restrict__ c1, int* __restrict__ r1, int n1,
                                                     const int* __restrict__ c2, int* __restrict__ r2, int n2,
                                                     const int* __restrict__ c3, int* __restrict__ r3, int n3) {
    const int* cnt; int* rs; int n;
    if (blockIdx.x == 0) { cnt = c1; rs = r1; n = n1; }
    else if (blockIdx.x == 1) { cnt = c2; rs = r2; n = n2; }
    else { cnt = c3; rs = r3; n = n3; }
    __shared__ int buf[1024];
    __shared__ int carry_s;
    int tid = threadIdx.x;
    if (tid == 0) { carry_s = 0; rs[0] = 0; }
    __syncthreads();
    for (int base = 0; base < n; base += 4096) {
        int i0 = base + tid * 4;
        int v[4];
#pragma unroll
        for (int q = 0; q < 4; ++q) { int i = i0 + q; v[q] = (i < n) ? cnt[i] : 0; }
        int s = v[0] + v[1] + v[2] + v[3];
        buf[tid] = s;
        __syncthreads();
        for (int off = 1; off < 1024; off <<= 1) {
            int t = (tid >= off) ? buf[tid - off] : 0;
            __syncthreads();
            buf[tid] += t;
            __syncthreads();
        }
        int carry = carry_s;
        int excl = carry + buf[tid] - s;
#pragma unroll
        for (int q = 0; q < 4; ++q) { int i = i0 + q; excl += v[q]; if (i < n) rs[i + 1] = excl; }
        int total = buf[1023];
        __syncthreads();
        if (tid == 0) carry_s = carry + total;
        __syncthreads();
    }
}

// ---------------- 3-graph edge bucketing ----------------
__global__ void bucket_all(const int* __restrict__ s1, const int* __restrict__ d1,
                           const int* __restrict__ r1, int* __restrict__ u1, int* __restrict__ e1,
                           const int* __restrict__ s2, const int* __restrict__ d2,
                           const int* __restrict__ r2, int* __restrict__ u2, int* __restrict__ e2,
                           const int* __restrict__ s3, const int* __restrict__ d3,
                           const int* __restrict__ r3, int* __restrict__ u3, int* __restrict__ e3) {
    int i0 = blockIdx.x * blockDim.x + threadIdx.x;
    int stride = gridDim.x * blockDim.x;
    for (int i = i0; i < EII; i += stride) {
        int d = d1[i]; int p = atomicAdd(&u1[d], 1); e1[r1[d] + p] = s1[i];
    }
    for (int i = i0; i < EIU0; i += stride) {
        int d = d2[i];
        if (d < NU1) { int p = atomicAdd(&u2[d], 1); e2[r2[d] + p] = s2[i]; }
    }
    for (int i = i0; i < EIU1; i += stride) {
        int d = d3[i]; int p = atomicAdd(&u3[d], 1); e3[r3[d] + p] = s3[i];
    }
}

// ---------------- wave-per-row mean gather: 2 edges/iter, 16B/lane ----------------
__global__ __launch_bounds__(256) void gather_csr(const unsigned short* __restrict__ X,
                                                  const int* __restrict__ csr,
                                                  const int* __restrict__ rs,
                                                  unsigned short* __restrict__ out, int nrows) {
    int wid = (blockIdx.x * blockDim.x + threadIdx.x) >> 6;
    int lane = threadIdx.x & 63;
    if (wid >= nrows) return;
    int s = rs[wid], e = rs[wid + 1];
    const int half = lane >> 5;     // 0 or 1: which edge of the pair
    const int l32 = lane & 31;      // 32 lanes x 16B = 512B row
    float acc[8] = {};
    for (int j = s; j < e; j += 64) {
        int myid = (j + lane < e) ? csr[j + lane] : 0;
        int cnt = min(64, e - j);
        int tmax = min(32, cnt);
        for (int t = 0; t < tmax; ++t) {
            int idx = t + half * 32;
            int sid = __shfl(myid, idx, 64);
            if (idx < cnt) {
                const uint4 v = *reinterpret_cast<const uint4*>(X + (size_t)sid * D + l32 * 8);
                acc[0] += bflo(v.x); acc[1] += bfhi(v.x);
                acc[2] += bflo(v.y); acc[3] += bfhi(v.y);
                acc[4] += bflo(v.z); acc[5] += bfhi(v.z);
                acc[6] += bflo(v.w); acc[7] += bfhi(v.w);
            }
        }
    }
#pragma unroll
    for (int q = 0; q < 8; ++q) acc[q] += __shfl_xor(acc[q], 32, 64);
    if (half == 0) {
        float r = 1.0f / fmaxf((float)(e - s), 1.0f);
        uint4 o;
        o.x = f2bf(acc[0] * r) | ((unsigned)f2bf(acc[1] * r) << 16);
        o.y = f2bf(acc[2] * r) | ((unsigned)f2bf(acc[3] * r) << 16);
        o.z = f2bf(acc[4] * r) | ((unsigned)f2bf(acc[5] * r) << 16);
        o.w = f2bf(acc[6] * r) | ((unsigned)f2bf(acc[7] * r) << 16);
        *reinterpret_cast<uint4*>(out + (size_t)wid * D + l32 * 8) = o;
    }
}

// ---------------- MFMA SAGE GEMM ----------------
// C = act( A1 @ W1t' + A2 @ W2t' + bias ),  Wt stored [n][k], K=256
template<bool A1F32, bool HAS_AGG, bool RELU, bool OUTF32>
__global__ __launch_bounds__(256) void sage_gemm(
    const unsigned short* __restrict__ A1b, const float* __restrict__ A1f,
    const unsigned short* __restrict__ A2,
    const unsigned short* __restrict__ W1t, const unsigned short* __restrict__ W2t,
    const float* __restrict__ bias,
    unsigned short* __restrict__ Cb, float* __restrict__ Cf,
    int M, int N)
{
    __shared__ unsigned short sA[128 * 40];  // [row][40] padded, 80B stride
    __shared__ unsigned short sB[128 * 40];  // [n][40]
    const int tid = threadIdx.x;
    const int lane = tid & 63;
    const int wid = tid >> 6;
    const int wrow = (wid >> 1) * 64;
    const int wcol = (wid & 1) * 64;
    const int brow = blockIdx.x * 128;
    const int bcol = blockIdx.y * 128;

    f32x4 acc[4][4] = {};

    const int r0 = tid >> 2;        // 0..63
    const int k0 = (tid & 3) * 8;   // 0,8,16,24

    const int nPass = HAS_AGG ? 2 : 1;
    for (int pass = 0; pass < nPass; ++pass) {
        const unsigned short* __restrict__ Wt = pass ? W2t : W1t;
        for (int kt = 0; kt < 256; kt += 32) {
#pragma unroll
            for (int c = 0; c < 2; ++c) {
                int row = r0 + c * 64;
                int grow = brow + row;
                uint4 val = {0u, 0u, 0u, 0u};
                if (pass == 0) {
                    if (A1F32) {
                        if (grow < M) {
                            const float4 f1 = *reinterpret_cast<const float4*>(A1f + (size_t)grow * 256 + kt + k0);
                            const float4 f2 = *reinterpret_cast<const float4*>(A1f + (size_t)grow * 256 + kt + k0 + 4);
                            val.x = f2bf(f1.x) | ((unsigned)f2bf(f1.y) << 16);
                            val.y = f2bf(f1.z) | ((unsigned)f2bf(f1.w) << 16);
                            val.z = f2bf(f2.x) | ((unsigned)f2bf(f2.y) << 16);
                            val.w = f2bf(f2.z) | ((unsigned)f2bf(f2.w) << 16);
                        }
                    } else {
                        if (grow < M) val = *reinterpret_cast<const uint4*>(A1b + (size_t)grow * 256 + kt + k0);
                    }
                } else {
                    if (grow < M) val = *reinterpret_cast<const uint4*>(A2 + (size_t)grow * 256 + kt + k0);
                }
                *reinterpret_cast<uint4*>(sA + row * 40 + k0) = val;
                *reinterpret_cast<uint4*>(sB + row * 40 + k0) =
                    *reinterpret_cast<const uint4*>(Wt + (size_t)(bcol + row) * 256 + kt + k0);
            }
            __syncthreads();
            const int fr = lane & 15;
            const int fk = (lane >> 4) * 8;
            bf16x8 af[4], bfr[4];
#pragma unroll
            for (int f = 0; f < 4; ++f) {
                af[f]  = __builtin_bit_cast(bf16x8, *reinterpret_cast<const uint4*>(sA + (wrow + f * 16 + fr) * 40 + fk));
                bfr[f] = __builtin_bit_cast(bf16x8, *reinterpret_cast<const uint4*>(sB + (wcol + f * 16 + fr) * 40 + fk));
            }
#pragma unroll
            for (int mi = 0; mi < 4; ++mi)
#pragma unroll
                for (int ni = 0; ni < 4; ++ni)
                    acc[mi][ni] = __builtin_amdgcn_mfma_f32_16x16x32_bf16(af[mi], bfr[ni], acc[mi][ni], 0, 0, 0);
            __syncthreads();
        }
    }

    const int cr = (lane >> 4) * 4;
    const int cc = lane & 15;
#pragma unroll
    for (int mi = 0; mi < 4; ++mi) {
#pragma unroll
        for (int j = 0; j < 4; ++j) {
            int grow = brow + wrow + mi * 16 + cr + j;
            if (grow >= M) continue;
#pragma unroll
            for (int ni = 0; ni < 4; ++ni) {
                int gcol = bcol + wcol + ni * 16 + cc;
                float v = acc[mi][ni][j] + bias[gcol];
                if (RELU) v = fmaxf(v, 0.f);
                if (OUTF32) Cf[(size_t)grow * N + gcol] = v;
                else Cb[(size_t)grow * N + gcol] = f2bf(v);
            }
        }
    }
}

extern "C" void kernel_launch(void* const* d_in, const int* in_sizes, int n_in,
                              void* d_out, int out_size, void* d_ws, size_t ws_size,
                              hipStream_t stream) {
    const float* x_item = (const float*)d_in[0];
    const float* x_user = (const float*)d_in[1];
    const int* src_ii  = (const int*)d_in[2];
    const int* dst_ii  = (const int*)d_in[3];
    const int* src_iu0 = (const int*)d_in[4];
    const int* dst_iu0 = (const int*)d_in[5];
    const int* src_iu1 = (const int*)d_in[6];
    const int* dst_iu1 = (const int*)d_in[7];
    const float* Wn1 = (const float*)d_in[8];
    const float* Ws1 = (const float*)d_in[9];
    const float* b1  = (const float*)d_in[10];
    const float* Wn2 = (const float*)d_in[11];
    const float* Ws2 = (const float*)d_in[12];
    const float* b2  = (const float*)d_in[13];
    const float* Wn3 = (const float*)d_in[14];
    const float* Ws3 = (const float*)d_in[15];
    const float* b3  = (const float*)d_in[16];
    const float* Wlin = (const float*)d_in[17];
    const float* blin = (const float*)d_in[18];
    float* out = (float*)d_out;

    // ---- workspace layout (~117 MB) ----
    unsigned short* xb_item = (unsigned short*)d_ws;             // 100000*256
    unsigned short* aggbuf  = xb_item + (size_t)NI_SRC * D;      // 50000*256
    unsigned short* item_x  = aggbuf + (size_t)NI_DST * D;       // 50000*256
    unsigned short* user_x2 = item_x + (size_t)NI_DST * D;       // 25000*256 (12.8 MB)
    unsigned short* wts     = user_x2 + (size_t)NU1 * D;         // 6*65536 + 32768

    // CSR int scratch (9.2 MB) overlays user_x2 (written only at GEMM2, after all gathers)
    int* ib   = (int*)user_x2;
    int* cnt1 = ib;                 // 50000
    int* cnt2 = ib + 50000;         // 25000
    int* cnt3 = ib + 75000;         // 25000
    int* cur1 = ib + 100000;        // 50000
    int* cur2 = ib + 150000;        // 25000
    int* cur3 = ib + 175000;        // 25000
    int* rs1  = ib + 200000;        // 50001
    int* rs2  = ib + 250001;        // 25001
    int* rs3  = ib + 275002;        // 25001
    int* csr1 = ib + 300003;        // 800000
    int* csr2 = ib + 1100003;       // 800000 (worst case)
    int* csr3 = ib + 1900003;       // 400000  -> end 2300003 ints < 3.2M available

    unsigned short* Wt_s1 = wts;
    unsigned short* Wt_n1 = wts + 65536;
    unsigned short* Wt_s2 = wts + 2 * 65536;
    unsigned short* Wt_n2 = wts + 3 * 65536;
    unsigned short* Wt_s3 = wts + 4 * 65536;
    unsigned short* Wt_n3 = wts + 5 * 65536;
    unsigned short* Wt_li = wts + 6 * 65536;

    unsigned short* agg2 = aggbuf;                      // 25000*256
    unsigned short* agg3 = aggbuf + (size_t)NU1 * D;    // 25000*256
    unsigned short* user_x3 = aggbuf;                   // overlays dead agg2 during GEMM3

    // ---- conversions ----
    long n8 = (long)NI_SRC * D / 8;
    cvt_kernel<<<(int)((n8 + 255) / 256), 256, 0, stream>>>(x_item, xb_item, n8);
    wcvt_all<<<1664, 256, 0, stream>>>(Ws1, Wn1, Ws2, Wn2, Ws3, Wn3, Wlin, wts);

    // ---- CSR build: all 3 graphs fused ----
    hipMemsetAsync(ib, 0, sizeof(int) * 200000, stream);  // cnt1..3 + cur1..3
    hist_all<<<512, 256, 0, stream>>>(dst_ii, cnt1, dst_iu0, cnt2, dst_iu1, cnt3);
    scan3_kernel<<<3, 1024, 0, stream>>>(cnt1, rs1, NI_DST, cnt2, rs2, NU1, cnt3, rs3, NU1);
    bucket_all<<<512, 256, 0, stream>>>(src_ii, dst_ii, rs1, cur1, csr1,
                                        src_iu0, dst_iu0, rs2, cur2, csr2,
                                        src_iu1, dst_iu1, rs3, cur3, csr3);

    dim3 g1((NI_DST + 127) / 128, 2);
    dim3 g2((NU1 + 127) / 128, 2);
    dim3 g4((NU1 + 127) / 128, 1);

    // ---- layer 1 ----
    gather_csr<<<(NI_DST * 64 + 255) / 256, 256, 0, stream>>>(xb_item, csr1, rs1, aggbuf, NI_DST);
    sage_gemm<false, true, true, false><<<g1, 256, 0, stream>>>(
        xb_item, nullptr, aggbuf, Wt_s1, Wt_n1, b1, item_x, nullptr, NI_DST, D);

    // ---- gathers 2+3 (aggbuf free after GEMM1; item_x ready) ----
    gather_csr<<<(NU1 * 64 + 255) / 256, 256, 0, stream>>>(xb_item, csr2, rs2, agg2, NU1);
    gather_csr<<<(NU1 * 64 + 255) / 256, 256, 0, stream>>>(item_x, csr3, rs3, agg3, NU1);

    // ---- layer 2 (x_user f32 converted in staging; writes user_x2 -> CSR dead) ----
    sage_gemm<true, true, true, false><<<g2, 256, 0, stream>>>(
        nullptr, x_user, agg2, Wt_s2, Wt_n2, b2, user_x2, nullptr, NU1, D);

    // ---- layer 3 ----
    sage_gemm<false, true, true, false><<<g2, 256, 0, stream>>>(
        user_x2, nullptr, agg3, Wt_s3, Wt_n3, b3, user_x3, nullptr, NU1, D);

    // ---- head ----
    sage_gemm<false, false, false, true><<<g4, 256, 0, stream>>>(
        user_x3, nullptr, nullptr, Wt_li, nullptr, blin, nullptr, out, NU1, DOUT);
}